// Round 1
// baseline (375.607 us; speedup 1.0000x reference)
//
#include <hip/hip_runtime.h>
#include <hip/hip_bf16.h>
#include <stdint.h>

#define BATCH   2048
#define NF      16
#define EMBED   256
#define NPAIRS  120
#define OUTROW  (NPAIRS*EMBED)   /* 30720 */
#define EMBROW  (NF*EMBED)       /* 4096  */

typedef __attribute__((ext_vector_type(8))) __bf16 bf16x8;
typedef __attribute__((ext_vector_type(4))) float  f32x4;

typedef __attribute__((address_space(3))) void       lds_void;
typedef const __attribute__((address_space(1))) void g_void;

__device__ __forceinline__ unsigned short f2bf(float f) {
    unsigned u = __float_as_uint(f);
    u += 0x7FFF + ((u >> 16) & 1);   // round-to-nearest-even
    return (unsigned short)(u >> 16);
}

__device__ __forceinline__ void pair_rc(int p, int& r, int& c) {
    int rr = 0, base = 0;
    while (p >= base + (NF - 1 - rr)) { base += NF - 1 - rr; ++rr; }
    r = rr; c = rr + 1 + (p - base);
}

// ---------------- prepass 1: emb (B,NF,E) fp32 -> embp[f][e/8][b][8] bf16 ----------------
// Layout chosen so the main kernel's A-tile global_load_lds chunks (lane-contiguous,
// 16B each) land as LDS [kchunk][m][8] with conflict-free ds_read_b128 fragment reads.
__global__ __launch_bounds__(256) void emb_permute(const float* __restrict__ emb,
                                                   unsigned short* __restrict__ embp) {
    __shared__ float tile[64][65];
    const int b0 = blockIdx.x * 64;
    const int e0 = blockIdx.y * 64;
    const int f  = blockIdx.z;
    const int t  = threadIdx.x;
#pragma unroll
    for (int rnd = 0; rnd < 4; ++rnd) {
        int bl = rnd * 16 + (t >> 4);
        int el = (t & 15) * 4;
        const float4 v = *(const float4*)(emb + (size_t)(b0 + bl) * EMBROW + f * EMBED + e0 + el);
        tile[bl][el] = v.x; tile[bl][el + 1] = v.y; tile[bl][el + 2] = v.z; tile[bl][el + 3] = v.w;
    }
    __syncthreads();
#pragma unroll
    for (int rnd = 0; rnd < 2; ++rnd) {
        int ec = rnd * 4 + (t >> 6);   // 0..7 within tile
        int bl = t & 63;
        unsigned short h[8];
#pragma unroll
        for (int i = 0; i < 8; ++i) h[i] = f2bf(tile[bl][ec * 8 + i]);
        uint4 w;
        w.x = h[0] | ((unsigned)h[1] << 16);
        w.y = h[2] | ((unsigned)h[3] << 16);
        w.z = h[4] | ((unsigned)h[5] << 16);
        w.w = h[6] | ((unsigned)h[7] << 16);
        *(uint4*)(embp + (size_t)f * (32u * BATCH * 8) + (size_t)(e0 / 8 + ec) * (BATCH * 8)
                        + (size_t)(b0 + bl) * 8) = w;
    }
}

// ---------------- prepass 2: weight (P,E,E) fp32 -> wtp[p][e/8][f][8] bf16 ----------------
__global__ __launch_bounds__(256) void wt_permute(const float* __restrict__ wt,
                                                  unsigned short* __restrict__ wtp) {
    __shared__ float tile[64][65];   // [e][f]
    const int e0 = blockIdx.x * 64;
    const int f0 = blockIdx.y * 64;
    const int p  = blockIdx.z;
    const int t  = threadIdx.x;
#pragma unroll
    for (int rnd = 0; rnd < 4; ++rnd) {
        int el = rnd * 16 + (t >> 4);
        int fl = (t & 15) * 4;
        const float4 v = *(const float4*)(wt + (size_t)p * (EMBED * EMBED) + (size_t)(e0 + el) * EMBED + f0 + fl);
        tile[el][fl] = v.x; tile[el][fl + 1] = v.y; tile[el][fl + 2] = v.z; tile[el][fl + 3] = v.w;
    }
    __syncthreads();
#pragma unroll
    for (int rnd = 0; rnd < 2; ++rnd) {
        int ec = rnd * 4 + (t >> 6);   // 0..7: e-chunk within tile
        int fl = t & 63;
        unsigned short h[8];
#pragma unroll
        for (int i = 0; i < 8; ++i) h[i] = f2bf(tile[ec * 8 + i][fl]);   // column read, stride 65: conflict-free
        uint4 w;
        w.x = h[0] | ((unsigned)h[1] << 16);
        w.y = h[2] | ((unsigned)h[3] << 16);
        w.z = h[4] | ((unsigned)h[5] << 16);
        w.w = h[6] | ((unsigned)h[7] << 16);
        *(uint4*)(wtp + (size_t)p * (EMBED * EMBED) + (size_t)(e0 / 8 + ec) * (EMBED * 8)
                       + (size_t)(f0 + fl) * 8) = w;
    }
}

// ---------------- main: per (pair, mblk, nblk): 128x128 tile of C = A_r @ W_p, fused *q + bias ----------------
__global__ __launch_bounds__(256) void bilinear_main(
        const float* __restrict__ emb, const float* __restrict__ bias,
        const unsigned short* __restrict__ embp, const unsigned short* __restrict__ wtp,
        float* __restrict__ out) {
    __shared__ __align__(16) unsigned short a_lds[4 * 128 * 8];  // [kc][m][8] bf16, 8KB
    __shared__ __align__(16) unsigned short b_lds[4 * 128 * 8];  // [kc][n][8] bf16, 8KB

    const int nblk = blockIdx.x, mblk = blockIdx.y, p = blockIdx.z;
    int r, c; pair_rc(p, r, c);
    const int m0 = mblk * 128, n0 = nblk * 128;
    const int t = threadIdx.x;
    const int wave = t >> 6, lane = t & 63;
    const int wm = (wave >> 1) * 64, wn = (wave & 1) * 64;
    const int kq = lane >> 4, l15 = lane & 15;

    const unsigned short* a_base = embp + (size_t)r * (32u * BATCH * 8);
    const unsigned short* b_base = wtp + (size_t)p * (EMBED * EMBED);

    f32x4 acc[4][4] = {};

#pragma unroll 1
    for (int ki = 0; ki < 8; ++ki) {   // K = 256, BK = 32
        // stage A & B tiles: 512 chunks each of 16B; 2 insts/thread/operand
#pragma unroll
        for (int i = 0; i < 2; ++i) {
            int q  = i * 256 + t;            // chunk = kc*128 + rowlocal
            int kc = q >> 7, xl = q & 127;
            const unsigned short* ga = a_base + (size_t)(ki * 4 + kc) * (BATCH * 8) + (size_t)(m0 + xl) * 8;
            __builtin_amdgcn_global_load_lds((g_void*)ga, (lds_void*)(a_lds + q * 8), 16, 0, 0);
            const unsigned short* gb = b_base + (size_t)(ki * 4 + kc) * (EMBED * 8) + (size_t)(n0 + xl) * 8;
            __builtin_amdgcn_global_load_lds((g_void*)gb, (lds_void*)(b_lds + q * 8), 16, 0, 0);
        }
        __syncthreads();

        bf16x8 af[4], bfr[4];
#pragma unroll
        for (int i = 0; i < 4; ++i)
            af[i] = *(const bf16x8*)(a_lds + (kq * 128 + wm + i * 16 + l15) * 8);
#pragma unroll
        for (int j = 0; j < 4; ++j)
            bfr[j] = *(const bf16x8*)(b_lds + (kq * 128 + wn + j * 16 + l15) * 8);
#pragma unroll
        for (int i = 0; i < 4; ++i)
#pragma unroll
            for (int j = 0; j < 4; ++j)
                acc[i][j] = __builtin_amdgcn_mfma_f32_16x16x32_bf16(af[i], bfr[j], acc[i][j], 0, 0, 0);
        __syncthreads();
    }

    // epilogue: out[m, p, n] = acc * emb[m, c, n] + bias[p, n]
    float bv[4];
#pragma unroll
    for (int j = 0; j < 4; ++j)
        bv[j] = bias[p * EMBED + n0 + wn + j * 16 + l15];

#pragma unroll
    for (int i = 0; i < 4; ++i) {
#pragma unroll
        for (int reg = 0; reg < 4; ++reg) {
            const int row = m0 + wm + i * 16 + kq * 4 + reg;     // C/D: row=(lane>>4)*4+reg
            const float* qrow = emb + (size_t)row * EMBROW + c * EMBED + n0;
            float* orow = out + (size_t)row * OUTROW + p * EMBED + n0;
#pragma unroll
            for (int j = 0; j < 4; ++j) {
                const int col = wn + j * 16 + l15;               // C/D: col=lane&15
                orow[col] = acc[i][j][reg] * qrow[col] + bv[j];
            }
        }
    }
}

extern "C" void kernel_launch(void* const* d_in, const int* in_sizes, int n_in,
                              void* d_out, int out_size, void* d_ws, size_t ws_size,
                              hipStream_t stream) {
    const float* emb    = (const float*)d_in[0];
    const float* weight = (const float*)d_in[1];
    const float* bias   = (const float*)d_in[2];
    float* out = (float*)d_out;

    // workspace: wtp (120*256*256 bf16 = 15,728,640 B) then embp (16*32*2048*8 bf16 = 16,777,216 B)
    unsigned short* wtp  = (unsigned short*)d_ws;
    unsigned short* embp = (unsigned short*)((char*)d_ws + 15728640);

    wt_permute<<<dim3(4, 4, NPAIRS), 256, 0, stream>>>(weight, wtp);
    emb_permute<<<dim3(BATCH / 64, EMBED / 64, NF), 256, 0, stream>>>(emb, embp);
    bilinear_main<<<dim3(2, BATCH / 128, NPAIRS), 256, 0, stream>>>(emb, bias, embp, wtp, out);
}

// Round 3
// 342.934 us; speedup vs baseline: 1.0953x; 1.0953x over previous
//
#include <hip/hip_runtime.h>
#include <hip/hip_bf16.h>
#include <stdint.h>

#define BATCH   2048
#define NF      16
#define EMBED   256
#define NPAIRS  120
#define OUTROW  (NPAIRS*EMBED)   /* 30720 */
#define EMBROW  (NF*EMBED)       /* 4096  */

typedef __attribute__((ext_vector_type(8))) __bf16 bf16x8;
typedef __attribute__((ext_vector_type(4))) float  f32x4;

typedef __attribute__((address_space(3))) void       lds_void;
typedef const __attribute__((address_space(1))) void g_void;

__device__ __forceinline__ unsigned short f2bf(float f) {
    unsigned u = __float_as_uint(f);
    u += 0x7FFF + ((u >> 16) & 1);   // round-to-nearest-even
    return (unsigned short)(u >> 16);
}

__device__ __forceinline__ void pair_rc(int p, int& r, int& c) {
    int rr = 0, base = 0;
    while (p >= base + (NF - 1 - rr)) { base += NF - 1 - rr; ++rr; }
    r = rr; c = rr + 1 + (p - base);
}

// ---------------- prepass 1: emb (B,NF,E) fp32 -> embp[f][e/8][b][8] bf16 ----------------
__global__ __launch_bounds__(256) void emb_permute(const float* __restrict__ emb,
                                                   unsigned short* __restrict__ embp) {
    __shared__ float tile[64][65];
    const int b0 = blockIdx.x * 64;
    const int e0 = blockIdx.y * 64;
    const int f  = blockIdx.z;
    const int t  = threadIdx.x;
#pragma unroll
    for (int rnd = 0; rnd < 4; ++rnd) {
        int bl = rnd * 16 + (t >> 4);
        int el = (t & 15) * 4;
        const float4 v = *(const float4*)(emb + (size_t)(b0 + bl) * EMBROW + f * EMBED + e0 + el);
        tile[bl][el] = v.x; tile[bl][el + 1] = v.y; tile[bl][el + 2] = v.z; tile[bl][el + 3] = v.w;
    }
    __syncthreads();
#pragma unroll
    for (int rnd = 0; rnd < 2; ++rnd) {
        int ec = rnd * 4 + (t >> 6);   // 0..7 within tile
        int bl = t & 63;
        unsigned short h[8];
#pragma unroll
        for (int i = 0; i < 8; ++i) h[i] = f2bf(tile[bl][ec * 8 + i]);
        uint4 w;
        w.x = h[0] | ((unsigned)h[1] << 16);
        w.y = h[2] | ((unsigned)h[3] << 16);
        w.z = h[4] | ((unsigned)h[5] << 16);
        w.w = h[6] | ((unsigned)h[7] << 16);
        *(uint4*)(embp + (size_t)f * (32u * BATCH * 8) + (size_t)(e0 / 8 + ec) * (BATCH * 8)
                        + (size_t)(b0 + bl) * 8) = w;
    }
}

// ---------------- prepass 2: weight (P,E,E) fp32 -> wtp[p][e/8][f][8] bf16 ----------------
__global__ __launch_bounds__(256) void wt_permute(const float* __restrict__ wt,
                                                  unsigned short* __restrict__ wtp) {
    __shared__ float tile[64][65];   // [e][f]
    const int e0 = blockIdx.x * 64;
    const int f0 = blockIdx.y * 64;
    const int p  = blockIdx.z;
    const int t  = threadIdx.x;
#pragma unroll
    for (int rnd = 0; rnd < 4; ++rnd) {
        int el = rnd * 16 + (t >> 4);
        int fl = (t & 15) * 4;
        const float4 v = *(const float4*)(wt + (size_t)p * (EMBED * EMBED) + (size_t)(e0 + el) * EMBED + f0 + fl);
        tile[el][fl] = v.x; tile[el][fl + 1] = v.y; tile[el][fl + 2] = v.z; tile[el][fl + 3] = v.w;
    }
    __syncthreads();
#pragma unroll
    for (int rnd = 0; rnd < 2; ++rnd) {
        int ec = rnd * 4 + (t >> 6);   // 0..7: e-chunk within tile
        int fl = t & 63;
        unsigned short h[8];
#pragma unroll
        for (int i = 0; i < 8; ++i) h[i] = f2bf(tile[ec * 8 + i][fl]);   // row read, conflict-free
        uint4 w;
        w.x = h[0] | ((unsigned)h[1] << 16);
        w.y = h[2] | ((unsigned)h[3] << 16);
        w.z = h[4] | ((unsigned)h[5] << 16);
        w.w = h[6] | ((unsigned)h[7] << 16);
        *(uint4*)(wtp + (size_t)p * (EMBED * EMBED) + (size_t)(e0 / 8 + ec) * (EMBED * 8)
                       + (size_t)(f0 + fl) * 8) = w;
    }
}

// ---------------- main: per (pair, mblk, nblk): 128x128 tile of C = A_r @ W_p, fused *q + bias ----------------
__global__ __launch_bounds__(256) void bilinear_main(
        const float* __restrict__ emb, const float* __restrict__ bias,
        const unsigned short* __restrict__ embp, const unsigned short* __restrict__ wtp,
        float* __restrict__ out) {
    __shared__ __align__(16) unsigned short a_lds[4 * 128 * 8];  // [kc][m][8] bf16, 8KB
    __shared__ __align__(16) unsigned short b_lds[4 * 128 * 8];  // [kc][n][8] bf16, 8KB
    __shared__ __align__(16) float ep[4][16 * 66];               // per-wave epilogue slab, 16.9KB

    const int nblk = blockIdx.x, mblk = blockIdx.y, p = blockIdx.z;
    int r, c; pair_rc(p, r, c);
    const int m0 = mblk * 128, n0 = nblk * 128;
    const int t = threadIdx.x;
    const int wave = t >> 6, lane = t & 63;
    const int wm = (wave >> 1) * 64, wn = (wave & 1) * 64;
    const int kq = lane >> 4, l15 = lane & 15;

    const unsigned short* a_base = embp + (size_t)r * (32u * BATCH * 8);
    const unsigned short* b_base = wtp + (size_t)p * (EMBED * EMBED);

    f32x4 acc[4][4] = {};

#pragma unroll 1
    for (int ki = 0; ki < 8; ++ki) {   // K = 256, BK = 32
#pragma unroll
        for (int i = 0; i < 2; ++i) {
            int q  = i * 256 + t;            // chunk = kc*128 + rowlocal
            int kc = q >> 7, xl = q & 127;
            const unsigned short* ga = a_base + (size_t)(ki * 4 + kc) * (BATCH * 8) + (size_t)(m0 + xl) * 8;
            __builtin_amdgcn_global_load_lds((g_void*)ga, (lds_void*)(a_lds + q * 8), 16, 0, 0);
            const unsigned short* gb = b_base + (size_t)(ki * 4 + kc) * (EMBED * 8) + (size_t)(n0 + xl) * 8;
            __builtin_amdgcn_global_load_lds((g_void*)gb, (lds_void*)(b_lds + q * 8), 16, 0, 0);
        }
        __syncthreads();

        bf16x8 af[4], bfr[4];
#pragma unroll
        for (int i = 0; i < 4; ++i)
            af[i] = *(const bf16x8*)(a_lds + (kq * 128 + wm + i * 16 + l15) * 8);
#pragma unroll
        for (int j = 0; j < 4; ++j)
            bfr[j] = *(const bf16x8*)(b_lds + (kq * 128 + wn + j * 16 + l15) * 8);
#pragma unroll
        for (int i = 0; i < 4; ++i)
#pragma unroll
            for (int j = 0; j < 4; ++j)
                acc[i][j] = __builtin_amdgcn_mfma_f32_16x16x32_bf16(af[i], bfr[j], acc[i][j], 0, 0, 0);
        __syncthreads();
    }

    // ---- epilogue: LDS-transpose per wave slab -> f32x4 q loads, f32x4 NT stores ----
    // out[m, p, n] = acc * emb[m, c, n] + bias[p, n]
    const int lrow4 = lane >> 4;         // 0..3
    const int lcol  = (lane & 15) * 4;   // 0,4,...,60 (4 consecutive cols per thread)
    const f32x4 bv = *(const f32x4*)(bias + p * EMBED + n0 + wn + lcol);

#pragma unroll
    for (int i = 0; i < 4; ++i) {
        // scatter C/D fragments into slab: row=(lane>>4)*4+reg, col=j*16+l15
#pragma unroll
        for (int j = 0; j < 4; ++j)
#pragma unroll
            for (int reg = 0; reg < 4; ++reg)
                ep[wave][(kq * 4 + reg) * 66 + j * 16 + l15] = acc[i][j][reg];
        // gather rows back vectorized (wave-private slab: in-order LDS pipe, no barrier)
#pragma unroll
        for (int rr = 0; rr < 4; ++rr) {
            const int lrow = rr * 4 + lrow4;              // 0..15
            const f32x4 v = *(const f32x4*)&ep[wave][lrow * 66 + lcol];
            const int row  = m0 + wm + i * 16 + lrow;
            const f32x4 q = *(const f32x4*)(emb + (size_t)row * EMBROW + c * EMBED + n0 + wn + lcol);
            f32x4 o = v * q + bv;
            __builtin_nontemporal_store(o, (f32x4*)(out + (size_t)row * OUTROW + p * EMBED + n0 + wn + lcol));
        }
    }
}

extern "C" void kernel_launch(void* const* d_in, const int* in_sizes, int n_in,
                              void* d_out, int out_size, void* d_ws, size_t ws_size,
                              hipStream_t stream) {
    const float* emb    = (const float*)d_in[0];
    const float* weight = (const float*)d_in[1];
    const float* bias   = (const float*)d_in[2];
    float* out = (float*)d_out;

    // workspace: wtp (120*256*256 bf16 = 15,728,640 B) then embp (16*32*2048*8 bf16 = 16,777,216 B)
    unsigned short* wtp  = (unsigned short*)d_ws;
    unsigned short* embp = (unsigned short*)((char*)d_ws + 15728640);

    wt_permute<<<dim3(4, 4, NPAIRS), 256, 0, stream>>>(weight, wtp);
    emb_permute<<<dim3(BATCH / 64, EMBED / 64, NF), 256, 0, stream>>>(emb, embp);
    bilinear_main<<<dim3(2, BATCH / 128, NPAIRS), 256, 0, stream>>>(emb, bias, embp, wtp, out);
}